// Round 1
// baseline (10448.863 us; speedup 1.0000x reference)
//
#include <hip/hip_runtime.h>
#include <stdint.h>

typedef unsigned short u16;
typedef __attribute__((ext_vector_type(8))) short bf16x8;
typedef __attribute__((ext_vector_type(4))) float f32x4;
typedef __attribute__((ext_vector_type(4))) u16 u16x4;

#define KD 1920   // H (also the K of every big GEMM phase)
#define G4 7680   // 4*H

__device__ __forceinline__ u16 f2bf(float f) {
  union { float f; uint32_t u; } v; v.f = f;
  uint32_t u = v.u;
  uint32_t r = u + 0x7fffu + ((u >> 16) & 1u);
  return (u16)(r >> 16);
}
__device__ __forceinline__ float bf2f(u16 h) {
  union { uint32_t u; float f; } v; v.u = ((uint32_t)h) << 16; return v.f;
}
__device__ __forceinline__ float sigm(float x) { return 1.f / (1.f + __expf(-x)); }
__device__ __forceinline__ float tanhfast(float x) {
  float t = __expf(-2.f * fabsf(x));
  float r = (1.f - t) / (1.f + t);
  return x < 0.f ? -r : r;
}

__device__ __forceinline__ bf16x8 frag_load(const u16* p) {
  return *(const bf16x8*)p;  // 16B aligned by construction
}
__device__ __forceinline__ bf16x8 frag_load(const float* p) {
  const float4* q = (const float4*)p;
  float4 a = q[0], b = q[1];
  bf16x8 r;
  r[0] = (short)f2bf(a.x); r[1] = (short)f2bf(a.y);
  r[2] = (short)f2bf(a.z); r[3] = (short)f2bf(a.w);
  r[4] = (short)f2bf(b.x); r[5] = (short)f2bf(b.y);
  r[6] = (short)f2bf(b.z); r[7] = (short)f2bf(b.w);
  return r;
}

// fp32 -> bf16 weight conversion (once per launch, if ws_size allows)
__global__ __launch_bounds__(256) void k_cvt(const float* __restrict__ in,
                                             u16* __restrict__ out, int n) {
  int i = (blockIdx.x * 256 + threadIdx.x) * 4;
  if (i + 3 < n) {
    float4 v = *(const float4*)(in + i);
    u16x4 o;
    o[0] = f2bf(v.x); o[1] = f2bf(v.y); o[2] = f2bf(v.z); o[3] = f2bf(v.w);
    *(u16x4*)(out + i) = o;
  }
}

__global__ __launch_bounds__(256) void k_zero(float* __restrict__ p) {
  p[(size_t)blockIdx.x * 256 + threadIdx.x] = 0.f;
}

// ins-select + per-atom MLP1+MLP2, emits X (bf16 [128,1920]) and ins (f32 [128,120])
__global__ __launch_bounds__(64) void k_mlp(
    const float* __restrict__ inputs, const float* __restrict__ prevb,
    const int* __restrict__ burn,
    const float* __restrict__ W1, const float* __restrict__ b1,
    const float* __restrict__ W2, const float* __restrict__ b2,
    u16* __restrict__ Xb0, float* __restrict__ insb, int t) {
  __shared__ float h1s[64];
  int ba = blockIdx.x;              // b*30 + a
  int b = ba / 30, a = ba % 30;
  int j = threadIdx.x;
  bool gt = (t <= *burn);
  const float* src = gt ? (inputs + (((size_t)ba) * 65 + t) * 4)
                        : (prevb + (size_t)ba * 4);
  float i0 = src[0], i1 = src[1], i2 = src[2], i3 = src[3];
  float h1 = b1[j] + i0 * W1[j * 4 + 0] + i1 * W1[j * 4 + 1] +
             i2 * W1[j * 4 + 2] + i3 * W1[j * 4 + 3];
  h1 = fmaxf(h1, 0.f);
  h1s[j] = h1;
  __syncthreads();
  float h2 = b2[j];
  const float* w2r = W2 + j * 64;
#pragma unroll 8
  for (int k = 0; k < 64; ++k) h2 += h1s[k] * w2r[k];
  h2 = fmaxf(h2, 0.f);
  Xb0[(size_t)b * KD + a * 64 + j] = f2bf(h2);
  if (j < 4) insb[(size_t)ba * 4 + j] = src[j];
}

// GEMM: C[128,N] = A[128,1920](bf16) . B[N,1920]^T. One wave/block: 4 m-tiles x 4 n-tiles.
// grid = (N/64, 2 /*m-halves*/, phases). Phase 0 -> C0 (+bias1+bias2), phase 1 -> C1.
// EPI==1: relu, bf16 out to Cb (single phase).
template <typename BT, int EPI>
__global__ __launch_bounds__(64) void k_gemm(
    const u16* __restrict__ A1, const BT* __restrict__ B1,
    const u16* __restrict__ A2, const BT* __restrict__ B2,
    const float* __restrict__ bias1, const float* __restrict__ bias2,
    float* __restrict__ C0, float* __restrict__ C1,
    u16* __restrict__ Cb, int ldc) {
  const int lane = threadIdx.x;
  const int ln = lane & 15;
  const int quad = lane >> 4;
  const int n0 = blockIdx.x * 64;
  const int mh = blockIdx.y * 64;
  const int phase = blockIdx.z;

  const u16* A = (phase == 0) ? A1 : A2;
  const BT* B = (phase == 0) ? B1 : B2;

  f32x4 acc[4][4] = {};

  const u16* a_base = A + (size_t)(mh + ln) * KD + quad * 8;
  const BT* b_base = B + (size_t)(n0 + ln) * KD + quad * 8;

  for (int k0 = 0; k0 < KD; k0 += 32) {
    bf16x8 bfr[4], afr[4];
#pragma unroll
    for (int nt = 0; nt < 4; ++nt)
      bfr[nt] = frag_load(b_base + (size_t)nt * 16 * KD + k0);
#pragma unroll
    for (int mt = 0; mt < 4; ++mt)
      afr[mt] = frag_load(a_base + (size_t)mt * 16 * KD + k0);
#pragma unroll
    for (int mt = 0; mt < 4; ++mt)
#pragma unroll
      for (int nt = 0; nt < 4; ++nt)
        acc[mt][nt] = __builtin_amdgcn_mfma_f32_16x16x32_bf16(
            afr[mt], bfr[nt], acc[mt][nt], 0, 0, 0);
  }

  if (EPI == 0) {
    float* C = (phase == 0) ? C0 : C1;
#pragma unroll
    for (int nt = 0; nt < 4; ++nt) {
      int n = n0 + nt * 16 + ln;
      float bias = 0.f;
      if (phase == 0) bias = bias1[n] + bias2[n];
#pragma unroll
      for (int mt = 0; mt < 4; ++mt)
#pragma unroll
        for (int r = 0; r < 4; ++r) {
          int m = mh + mt * 16 + quad * 4 + r;
          C[(size_t)m * ldc + n] = acc[mt][nt][r] + bias;
        }
    }
  } else {
#pragma unroll
    for (int nt = 0; nt < 4; ++nt) {
      int n = n0 + nt * 16 + ln;
      float bias = bias1[n];
#pragma unroll
      for (int mt = 0; mt < 4; ++mt)
#pragma unroll
        for (int r = 0; r < 4; ++r) {
          int m = mh + mt * 16 + quad * 4 + r;
          float v = fmaxf(acc[mt][nt][r] + bias, 0.f);
          Cb[(size_t)m * ldc + n] = f2bf(v);
        }
    }
  }
}

// LSTM cell elementwise: gates = gp0 + gp1 (phase partials); PyTorch order i,f,g,o
__global__ __launch_bounds__(256) void k_cell(
    const float* __restrict__ g0, const float* __restrict__ g1,
    float* __restrict__ c, u16* __restrict__ hb) {
  int idx = blockIdx.x * 256 + threadIdx.x;  // 0..128*1920-1
  int m = idx / KD, j = idx % KD;
  size_t r = (size_t)m * G4;
  float gi = g0[r + j] + g1[r + j];
  float gf = g0[r + KD + j] + g1[r + KD + j];
  float gg = g0[r + 2 * KD + j] + g1[r + 2 * KD + j];
  float go = g0[r + 3 * KD + j] + g1[r + 3 * KD + j];
  float cn = sigm(gf) * c[idx] + sigm(gi) * tanhfast(gg);
  float hn = sigm(go) * tanhfast(cn);
  c[idx] = cn;
  hb[idx] = f2bf(hn);
}

// W4 projection + bias + residual; writes output slice t and prev-buffer
__global__ __launch_bounds__(64) void k_w4out(
    const u16* __restrict__ x3, const float* __restrict__ W4,
    const float* __restrict__ b4, const float* __restrict__ insb,
    float* __restrict__ outp, float* __restrict__ prevb, int t) {
  int m = blockIdx.x / 15;
  int pb = blockIdx.x % 15;
  int lane = threadIdx.x;
  const u16* xr = x3 + (size_t)m * KD;
  float xv[30];
#pragma unroll
  for (int i = 0; i < 30; ++i) xv[i] = bf2f(xr[lane + 64 * i]);
#pragma unroll 1
  for (int pi = 0; pi < 8; ++pi) {
    int p = pb * 8 + pi;
    const float* wr = W4 + (size_t)p * KD;
    float s = 0.f;
#pragma unroll
    for (int i = 0; i < 30; ++i) s += xv[i] * wr[lane + 64 * i];
#pragma unroll
    for (int off = 32; off > 0; off >>= 1) s += __shfl_xor(s, off);
    if (lane == 0) {
      float v = s + b4[p] + insb[(size_t)m * 120 + p];
      outp[(((size_t)m * 30 + (p >> 2)) * 64 + t) * 4 + (p & 3)] = v;
      prevb[(size_t)m * 120 + p] = v;
    }
  }
}

extern "C" void kernel_launch(void* const* d_in, const int* in_sizes, int n_in,
                              void* d_out, int out_size, void* d_ws, size_t ws_size,
                              hipStream_t stream) {
  (void)in_sizes; (void)n_in; (void)out_size;
  const float* inputs = (const float*)d_in[0];
  const float* W1 = (const float*)d_in[1];
  const float* b1 = (const float*)d_in[2];
  const float* W2 = (const float*)d_in[3];
  const float* b2 = (const float*)d_in[4];
  const float* Wih = (const float*)d_in[5];
  const float* Whh = (const float*)d_in[6];
  const float* bih = (const float*)d_in[7];
  const float* bhh = (const float*)d_in[8];
  const float* W3 = (const float*)d_in[9];
  const float* b3 = (const float*)d_in[10];
  const float* W4 = (const float*)d_in[11];
  const float* b4 = (const float*)d_in[12];
  const int* burn = (const int*)d_in[14];
  float* outp = (float*)d_out;
  char* ws = (char*)d_ws;

  // workspace layout (zero-init region first: c state + h state)
  float* cbuf = (float*)ws;                       // 2*128*1920 f32  = 1966080 B
  u16* Hb0 = (u16*)(ws + 1966080);                // 128*1920 bf16   =  491520 B
  u16* Hb1 = Hb0 + 245760;                        //                 =  491520 B
  u16* Xb0 = Hb1 + 245760;                        // mlp out bf16
  u16* X3b = Xb0 + 245760;                        // W3 out bf16
  float* gp0 = (float*)(ws + 1966080 + 4 * 491520);  // gates partial 0 [128,7680] f32
  float* gp1 = gp0 + 128 * G4;                    // gates partial 1
  float* insb = gp1 + 128 * G4;                   // ins f32 [128,120]
  float* prevb = insb + 128 * 120;                // prev prediction f32 [128,120]
  const size_t base_need = 11919360;
  const size_t wbf_need = base_need + ((size_t)29491200 * 2 + 3686400) * 2;
  bool bf = (ws_size >= wbf_need);
  u16* WihB = (u16*)(ws + base_need);
  u16* WhhB = WihB + 29491200;
  u16* W3B = WhhB + 29491200;

  // zero c and h states (2949120 B = 737280 floats)
  hipLaunchKernelGGL(k_zero, dim3(2880), dim3(256), 0, stream, (float*)ws);

  if (bf) {
    hipLaunchKernelGGL(k_cvt, dim3(28800), dim3(256), 0, stream, Wih, WihB, 29491200);
    hipLaunchKernelGGL(k_cvt, dim3(28800), dim3(256), 0, stream, Whh, WhhB, 29491200);
    hipLaunchKernelGGL(k_cvt, dim3(3600), dim3(256), 0, stream, W3, W3B, 3686400);
  }

  for (int t = 0; t < 64; ++t) {
    hipLaunchKernelGGL(k_mlp, dim3(3840), dim3(64), 0, stream,
                       inputs, prevb, burn, W1, b1, W2, b2, Xb0, insb, t);
    for (int l = 0; l < 2; ++l) {
      const u16* Ax = (l == 0) ? Xb0 : Hb0;   // x input to this layer
      const u16* Ah = (l == 0) ? Hb0 : Hb1;   // recurrent h input
      if (bf) {
        hipLaunchKernelGGL((k_gemm<u16, 0>), dim3(120, 2, 2), dim3(64), 0, stream,
                           Ax, WihB + (size_t)l * 14745600,
                           Ah, WhhB + (size_t)l * 14745600,
                           bih + l * G4, bhh + l * G4,
                           gp0, gp1, (u16*)nullptr, G4);
      } else {
        hipLaunchKernelGGL((k_gemm<float, 0>), dim3(120, 2, 2), dim3(64), 0, stream,
                           Ax, Wih + (size_t)l * 14745600,
                           Ah, Whh + (size_t)l * 14745600,
                           bih + l * G4, bhh + l * G4,
                           gp0, gp1, (u16*)nullptr, G4);
      }
      hipLaunchKernelGGL(k_cell, dim3(960), dim3(256), 0, stream,
                         gp0, gp1, cbuf + (size_t)l * 245760,
                         (l == 0) ? Hb0 : Hb1);
    }
    if (bf) {
      hipLaunchKernelGGL((k_gemm<u16, 1>), dim3(30, 2, 1), dim3(64), 0, stream,
                         Hb1, W3B, (const u16*)nullptr, (const u16*)nullptr,
                         b3, (const float*)nullptr,
                         (float*)nullptr, (float*)nullptr, X3b, KD);
    } else {
      hipLaunchKernelGGL((k_gemm<float, 1>), dim3(30, 2, 1), dim3(64), 0, stream,
                         Hb1, W3, (const u16*)nullptr, (const float*)nullptr,
                         b3, (const float*)nullptr,
                         (float*)nullptr, (float*)nullptr, X3b, KD);
    }
    hipLaunchKernelGGL(k_w4out, dim3(1920), dim3(64), 0, stream,
                       X3b, W4, b4, insb, outp, prevb, t);
  }
}